// Round 13
// baseline (186.862 us; speedup 1.0000x reference)
//
#include <hip/hip_runtime.h>
#include <hip/hip_bf16.h>
#include <math.h>

// ---------------------------------------------------------------------------
// MoE gate via fp16 hi/lo split MFMA (validated numerics, rounds 5-12):
//   x = xh + xl/2048,  W*64 = wh + wl/2048
//   logit = ( xh·wh + (xh·wl + xl·wh)/2048 ) / 64
// Round 13: PRODUCT-SPLIT ACROSS DISPATCHES. The cross accumulator's chain
// noise reaches the logit /2048/64 -> negligible at any chain length; only
// hi·hi needs chain<=28. Each dispatch is a SINGLE-accumulator GEMM (128
// VGPR) -> 256x256 tile, wave 128x64, fat 32/64-MFMA clusters:
//   gemm<HI>   : Spart[ks]  = sum xh·wh           (writes)
//   gemm<CROSS>: Spart[ks] += sum(xh·wl+xl·wh)/2048  (RMW, stream-ordered)
// Routing sums 8 partial sets in fp64, /64, sigmoid, grouped top-k.
// ---------------------------------------------------------------------------

typedef _Float16 f16x8 __attribute__((ext_vector_type(8)));
typedef float    f32x4 __attribute__((ext_vector_type(4)));

__device__ __forceinline__ void glds16(const void* g, void* l) {
  __builtin_amdgcn_global_load_lds(
      (const __attribute__((address_space(1))) void*)g,
      (__attribute__((address_space(3))) void*)l, 16, 0, 0);
}

__device__ __forceinline__ unsigned short f2h(float f) {
  _Float16 h = (_Float16)f;                       // v_cvt_f16_f32, RTN
  return __builtin_bit_cast(unsigned short, h);
}
__device__ __forceinline__ float h2f(unsigned short b) {
  return (float)__builtin_bit_cast(_Float16, b);
}

// swizzle: 64B rows, 4 granules of 16B; bijective in gi per row.
__device__ __forceinline__ int swz(int gi, int row) {
  return gi ^ (row & 3) ^ ((row >> 2) & 3);
}

// ---------------------------------------------------------------------------
// W [256][7168] fp32 -> Whi/Wlo fp16, 256-row pre-swizzled K-tiles (BK=32):
// K-tile t in 0..223 = 256 rows x 32 f16 = 8192 ushorts (16KB).
// element (r,k): gi=k>>3, addr = t*8192 + r*32 + swz(gi,r)*8 + (k&7).
// Whi = fp16(64*W); Wlo = fp16((64*W - Whi) * 2048).   (validated round 9)
// ---------------------------------------------------------------------------
__global__ __launch_bounds__(256) void convert_w(
    const float* __restrict__ W,
    unsigned short* __restrict__ Whi, unsigned short* __restrict__ Wlo)
{
  const int e = blockIdx.x;           // expert/row 0..255
  const int t = threadIdx.x;          // 0..255, use 224 (one K-tile each)
  if (t >= 224) return;
  const float* src = W + (size_t)e * 7168 + t * 32;
  const size_t tbase = (size_t)t * 8192 + (size_t)e * 32;
  #pragma unroll
  for (int g = 0; g < 4; ++g) {       // granule gi = g, k = g*8..g*8+7
    unsigned int hw[4], lw[4];
    #pragma unroll
    for (int p = 0; p < 4; ++p) {
      float f0 = src[g * 8 + 2 * p] * 64.0f;
      float f1 = src[g * 8 + 2 * p + 1] * 64.0f;
      unsigned short h0 = f2h(f0), h1 = f2h(f1);
      unsigned short l0 = f2h((f0 - h2f(h0)) * 2048.0f);
      unsigned short l1 = f2h((f1 - h2f(h1)) * 2048.0f);
      hw[p] = (unsigned)h0 | ((unsigned)h1 << 16);
      lw[p] = (unsigned)l0 | ((unsigned)l1 << 16);
    }
    const size_t base = tbase + (size_t)(swz(g, e) * 8);
    *(uint4*)(Whi + base) = make_uint4(hw[0], hw[1], hw[2], hw[3]);
    *(uint4*)(Wlo + base) = make_uint4(lw[0], lw[1], lw[2], lw[3]);
  }
}

// ---------------------------------------------------------------------------
// GEMM template: BM=256, BN=256, BK=32, K-split KS. 512 thr = 8 waves
// (2M x 4N), wave tile 128x64 = 8x4 frags of 16x16x32 f16 MFMA.
// HI:    LDS buf 32KB {Ahi 16K | Bh 16K},       32 MFMA/wave/tile, S  = acc
// CROSS: LDS buf 64KB {Ahi|Alo|Bh|Bl 16K each}, 64 MFMA/wave/tile, S += acc/2048
// A: fp32 global -> reg -> fp16 hi(/lo) -> swizzled ds_write (2 thr/row).
// B: glds from pre-swizzled 256-row tiles. r11-style counted-vmcnt loop.
// Grid 1-D: ks = bid % KS (XCD-affine), bm = bid / KS -> 256 blocks, 1/CU.
// ---------------------------------------------------------------------------
template<int CROSS>
__global__ __launch_bounds__(512, 2) void gate_gemm(
    const float* __restrict__ X,
    const unsigned short* __restrict__ Whi,
    const unsigned short* __restrict__ Wlo,
    float* __restrict__ Spart, int D, int TILES, int KS)
{
  extern __shared__ char lds[];
  const int BUF   = CROSS ? 65536 : 32768;
  const int O_ALO = 16384;                   // CROSS only
  const int O_BH  = CROSS ? 32768 : 16384;
  const int O_BL  = 49152;                   // CROSS only

  const int bid = blockIdx.x;
  const int ks = bid % KS;                   // XCD-affine for KS=8
  const int bm = bid / KS;
  const int tid = threadIdx.x, lane = tid & 63, wid = tid >> 6;
  const int wm = wid >> 2, wn = wid & 3;     // 2M x 4N wave grid
  const int TM = bm * 256;
  const int k0 = ks * TILES * 32;

  // A staging: 2 threads per row, 16 contiguous fp32 (granules 2h, 2h+1)
  const int srow = tid >> 1, half = tid & 1;
  const float* xsrc = X + (size_t)(TM + srow) * D + k0 + half * 16;
  const int aw0 = srow * 64 + swz(half * 2 + 0, srow) * 16;
  const int aw1 = srow * 64 + swz(half * 2 + 1, srow) * 16;

  const unsigned short* wh_tile = Whi + (size_t)(ks * TILES) * 8192;
  const unsigned short* wl_tile = Wlo + (size_t)(ks * TILES) * 8192;

  f32x4 acc[8][4];
  #pragma unroll
  for (int m = 0; m < 8; ++m)
    #pragma unroll
    for (int n = 0; n < 4; ++n) acc[m][n] = (f32x4)0.0f;

  // fragment read byte offsets, fixed per lane
  int aro[8], bro[4];
  const int gi = lane >> 4;
  #pragma unroll
  for (int m = 0; m < 8; ++m) {
    const int row = wm * 128 + m * 16 + (lane & 15);
    aro[m] = row * 64 + swz(gi, row) * 16;
  }
  #pragma unroll
  for (int n = 0; n < 4; ++n) {
    const int row = wn * 64 + n * 16 + (lane & 15);
    bro[n] = row * 64 + swz(gi, row) * 16;
  }

  float4 pa[4], pb[4];

  // ---- prologue: stage tile 0 into buf0; prefetch A(1) ----
  {
    #pragma unroll
    for (int i = 0; i < 2; ++i) {
      const int c = wid * 2 + i;             // chunk 0..15, wave-uniform
      glds16(wh_tile + c * 512 + lane * 8, lds + O_BH + c * 1024);
      if (CROSS) glds16(wl_tile + c * 512 + lane * 8, lds + O_BL + c * 1024);
    }
    __builtin_amdgcn_sched_barrier(0);
    float4 a[4];
    #pragma unroll
    for (int i = 0; i < 4; ++i) a[i] = *(const float4*)(xsrc + i * 4);
    unsigned int hw[8], lw[8];
    #pragma unroll
    for (int q = 0; q < 8; ++q) {
      float f0 = ((const float*)a)[2 * q], f1 = ((const float*)a)[2 * q + 1];
      unsigned short h0 = f2h(f0), h1 = f2h(f1);
      hw[q] = (unsigned)h0 | ((unsigned)h1 << 16);
      if (CROSS) {
        unsigned short l0 = f2h((f0 - h2f(h0)) * 2048.0f);
        unsigned short l1 = f2h((f1 - h2f(h1)) * 2048.0f);
        lw[q] = (unsigned)l0 | ((unsigned)l1 << 16);
      }
    }
    *(uint4*)(lds + aw0) = make_uint4(hw[0], hw[1], hw[2], hw[3]);
    *(uint4*)(lds + aw1) = make_uint4(hw[4], hw[5], hw[6], hw[7]);
    if (CROSS) {
      *(uint4*)(lds + O_ALO + aw0) = make_uint4(lw[0], lw[1], lw[2], lw[3]);
      *(uint4*)(lds + O_ALO + aw1) = make_uint4(lw[4], lw[5], lw[6], lw[7]);
    }
    const int s1 = (TILES > 1) ? 1 : 0;
    #pragma unroll
    for (int i = 0; i < 4; ++i)
      pa[i] = *(const float4*)(xsrc + (size_t)s1 * 32 + i * 4);
    __builtin_amdgcn_sched_barrier(0);
  }
  asm volatile("s_waitcnt vmcnt(4) lgkmcnt(0)" ::: "memory");
  __builtin_amdgcn_sched_barrier(0);
  __builtin_amdgcn_s_barrier();

  int cur = 0;
  for (int s = 0; s < TILES; ++s) {
    char* base_c = lds + cur * BUF;
    char* base_n = lds + (cur ^ 1) * BUF;
    const bool stage_next = (s + 1 < TILES);

    // 1. issue glds B(s+1) (oldest vmem this tile)
    if (stage_next) {
      const unsigned short* wh = wh_tile + (size_t)(s + 1) * 8192;
      const unsigned short* wl = wl_tile + (size_t)(s + 1) * 8192;
      #pragma unroll
      for (int i = 0; i < 2; ++i) {
        const int c = wid * 2 + i;
        glds16(wh + c * 512 + lane * 8, base_n + O_BH + c * 1024);
        if (CROSS) glds16(wl + c * 512 + lane * 8, base_n + O_BL + c * 1024);
      }
    }
    __builtin_amdgcn_sched_barrier(0);

    // 2. issue A(s+2) loads, clamped so exactly 4 are always in flight
    {
      int sn = s + 2; if (sn > TILES - 1) sn = TILES - 1;
      #pragma unroll
      for (int i = 0; i < 4; ++i)
        pb[i] = *(const float4*)(xsrc + (size_t)sn * 32 + i * 4);
    }
    __builtin_amdgcn_sched_barrier(0);

    // 3. compute from buf[cur]: per-m A frag read keeps registers bounded
    {
      f16x8 bh[4], bl[4];
      #pragma unroll
      for (int n = 0; n < 4; ++n) {
        bh[n] = *(const f16x8*)(base_c + O_BH + bro[n]);
        if (CROSS) bl[n] = *(const f16x8*)(base_c + O_BL + bro[n]);
      }
      __builtin_amdgcn_s_setprio(1);
      #pragma unroll
      for (int m = 0; m < 8; ++m) {
        f16x8 ah = *(const f16x8*)(base_c + aro[m]);
        if (!CROSS) {
          #pragma unroll
          for (int n = 0; n < 4; ++n)
            acc[m][n] = __builtin_amdgcn_mfma_f32_16x16x32_f16(ah, bh[n], acc[m][n], 0, 0, 0);
        } else {
          f16x8 al = *(const f16x8*)(base_c + O_ALO + aro[m]);
          #pragma unroll
          for (int n = 0; n < 4; ++n) {
            acc[m][n] = __builtin_amdgcn_mfma_f32_16x16x32_f16(ah, bl[n], acc[m][n], 0, 0, 0);
            acc[m][n] = __builtin_amdgcn_mfma_f32_16x16x32_f16(al, bh[n], acc[m][n], 0, 0, 0);
          }
        }
      }
      __builtin_amdgcn_s_setprio(0);
    }

    // 4. convert + ds_write A(s+1) into buf[nxt]
    if (stage_next) {
      unsigned int hw[8], lw[8];
      #pragma unroll
      for (int q = 0; q < 8; ++q) {
        float f0 = ((const float*)pa)[2 * q], f1 = ((const float*)pa)[2 * q + 1];
        unsigned short h0 = f2h(f0), h1 = f2h(f1);
        hw[q] = (unsigned)h0 | ((unsigned)h1 << 16);
        if (CROSS) {
          unsigned short l0 = f2h((f0 - h2f(h0)) * 2048.0f);
          unsigned short l1 = f2h((f1 - h2f(h1)) * 2048.0f);
          lw[q] = (unsigned)l0 | ((unsigned)l1 << 16);
        }
      }
      *(uint4*)(base_n + aw0) = make_uint4(hw[0], hw[1], hw[2], hw[3]);
      *(uint4*)(base_n + aw1) = make_uint4(hw[4], hw[5], hw[6], hw[7]);
      if (CROSS) {
        *(uint4*)(base_n + O_ALO + aw0) = make_uint4(lw[0], lw[1], lw[2], lw[3]);
        *(uint4*)(base_n + O_ALO + aw1) = make_uint4(lw[4], lw[5], lw[6], lw[7]);
      }
    }
    #pragma unroll
    for (int i = 0; i < 4; ++i) pa[i] = pb[i];

    // 5. counted drain + raw barrier: glds(s+1) done, A(s+2) stays in flight
    asm volatile("s_waitcnt vmcnt(4) lgkmcnt(0)" ::: "memory");
    __builtin_amdgcn_sched_barrier(0);
    __builtin_amdgcn_s_barrier();

    cur ^= 1;
  }

  // epilogue. C/D layout: col=lane&15 (expert), row=(lane>>4)*4+reg (token)
  float* Sp = Spart + (size_t)ks * 8192 * 256;
  #pragma unroll
  for (int m = 0; m < 8; ++m)
    #pragma unroll
    for (int n = 0; n < 4; ++n)
      #pragma unroll
      for (int r = 0; r < 4; ++r) {
        const int t = TM + wm * 128 + m * 16 + (lane >> 4) * 4 + r;
        const int e = wn * 64 + n * 16 + (lane & 15);
        if (CROSS)
          Sp[(size_t)t * 256 + e] += acc[m][n][r] * (1.0f / 2048.0f);
        else
          Sp[(size_t)t * 256 + e] = acc[m][n][r];
      }
}

// ---------------------------------------------------------------------------
// Routing: one wave per token. logit = (sum of KS fp32 partials, in DOUBLE)
// / 64; scores = sigmoid; grouped top-k (8 groups, top-2 group score,
// top-4 groups, top-8 experts, renorm * 2.5).   (validated rounds 5-12)
// ---------------------------------------------------------------------------
__global__ __launch_bounds__(256) void gate_routing(
    const float* __restrict__ Spart, int KS,
    const float* __restrict__ bias,
    float* __restrict__ outw, float* __restrict__ outi, int T)
{
  const int lane = threadIdx.x & 63;
  const int wave = threadIdx.x >> 6;
  const int t = blockIdx.x * 4 + wave;
  if (t >= T) return;

  double l[4] = {0.0, 0.0, 0.0, 0.0};
  for (int ks = 0; ks < KS; ++ks) {
    float4 p = *(const float4*)(Spart + (size_t)ks * T * 256
                                + (size_t)t * 256 + lane * 4);
    l[0] += (double)p.x; l[1] += (double)p.y;
    l[2] += (double)p.z; l[3] += (double)p.w;
  }

  float4 bi = *(const float4*)(bias + lane * 4);
  float orig[4], s[4];
  #pragma unroll
  for (int u = 0; u < 4; ++u)
    orig[u] = 1.0f / (1.0f + expf(-(float)(l[u] * (1.0 / 64.0))));
  s[0] = orig[0] + bi.x; s[1] = orig[1] + bi.y;
  s[2] = orig[2] + bi.z; s[3] = orig[3] + bi.w;

  // per-lane top-2 of its 4 biased scores
  float m1 = -INFINITY, m2 = -INFINITY;
  #pragma unroll
  for (int u = 0; u < 4; ++u) {
    float v = s[u];
    if (v > m1) { m2 = m1; m1 = v; }
    else if (v > m2) { m2 = v; }
  }
  // merge top-2 across the 8 lanes of the group
  #pragma unroll
  for (int off = 1; off < 8; off <<= 1) {
    float o1 = __shfl_xor(m1, off, 64);
    float o2 = __shfl_xor(m2, off, 64);
    if (o1 > m1) { m2 = fmaxf(m1, o2); m1 = o1; }
    else         { m2 = fmaxf(m2, o1); }
  }
  const float gscore = m1 + m2;

  const int g = lane >> 3;
  int rank = 0;
  #pragma unroll
  for (int j = 0; j < 8; ++j) {
    float gs = __shfl(gscore, j * 8, 64);
    rank += (gs > gscore || (gs == gscore && j < g)) ? 1 : 0;
  }
  if (rank >= 4) { s[0] = s[1] = s[2] = s[3] = -INFINITY; }

  float wsum = 0.0f, sel_w = 0.0f;
  int sel_i = 0;
  #pragma unroll
  for (int it = 0; it < 8; ++it) {
    float bv = s[0]; int bu = 0;
    #pragma unroll
    for (int u = 1; u < 4; ++u)
      if (s[u] > bv) { bv = s[u]; bu = u; }
    float v = bv;
    int ix = lane * 4 + bu;
    float og = orig[bu];
    #pragma unroll
    for (int off = 1; off < 64; off <<= 1) {
      float ov  = __shfl_xor(v,  off, 64);
      int   oix = __shfl_xor(ix, off, 64);
      float oog = __shfl_xor(og, off, 64);
      if (ov > v || (ov == v && oix < ix)) { v = ov; ix = oix; og = oog; }
    }
    if (lane == it) { sel_w = og; sel_i = ix; }
    wsum += og;
    if ((ix >> 2) == lane) s[ix & 3] = -INFINITY;
  }

  if (lane < 8) {
    outw[(size_t)t * 8 + lane] = sel_w / wsum * 2.5f;
    outi[(size_t)t * 8 + lane] = (float)sel_i;
  }
}

extern "C" void kernel_launch(void* const* d_in, const int* in_sizes, int n_in,
                              void* d_out, int out_size, void* d_ws, size_t ws_size,
                              hipStream_t stream) {
  const float* x = (const float*)d_in[0];
  const float* w = (const float*)d_in[1];
  const float* b = (const float*)d_in[2];
  const int E = in_sizes[2];                  // 256
  const int D = in_sizes[1] / E;              // 7168
  const int T = in_sizes[0] / D;              // 8192

  unsigned short* Whi = (unsigned short*)d_ws;                       // 3.67 MB
  unsigned short* Wlo = (unsigned short*)((char*)d_ws + (4u << 20)); // 3.67 MB
  float* Spart = (float*)((char*)d_ws + (8u << 20));                 // KS x 8 MB

  // adaptive K-split: largest of {8,4} that fits the workspace
  const size_t per_part = (size_t)T * E * 4;
  int KS = 4;
  if (ws_size >= (8u << 20) + 8 * per_part) KS = 8;
  const int TILES = D / (32 * KS);            // 28 for KS=8

  float* outw = (float*)d_out;
  float* outi = outw + (size_t)T * 8;

  convert_w<<<E, 256, 0, stream>>>(w, Whi, Wlo);
  const int grid = (T / 256) * KS;            // 256 blocks at KS=8 (1/CU)
  gate_gemm<0><<<grid, 512, 65536,  stream>>>(x, Whi, Wlo, Spart, D, TILES, KS);
  gate_gemm<1><<<grid, 512, 131072, stream>>>(x, Whi, Wlo, Spart, D, TILES, KS);
  gate_routing<<<(T + 3) / 4, 256, 0, stream>>>(Spart, KS, b, outw, outi, T);
}